// Round 19
// baseline (352.492 us; speedup 1.0000x reference)
//
#include <hip/hip_runtime.h>

#define NN 50000
#define EE 800000
#define FIN 128
#define HH 256
#define NL 3

#define BM 128                    // per block: 2 independent 64-row half-tiles
#define BK 32
#define TB (16384 + 8192)         // per staging buffer: B 16KB @0, A 8KB @16384
                                  // LDS = 3*TB = 72KB

typedef __bf16 bf16x8 __attribute__((ext_vector_type(8)));
typedef float  f32x4  __attribute__((ext_vector_type(4)));
typedef unsigned short u16x8 __attribute__((ext_vector_type(8)));
typedef unsigned short u16x4 __attribute__((ext_vector_type(4)));

__device__ __forceinline__ float bf2f(unsigned short u){
    union { unsigned int i; float f; } v; v.i = ((unsigned int)u) << 16; return v.f;
}
__device__ __forceinline__ unsigned short f2bf(float f){
    union { float f; unsigned int i; } v; v.f = f;
    unsigned int r = v.i + 0x7FFF + ((v.i >> 16) & 1);  // RNE
    return (unsigned short)(r >> 16);
}
__device__ __forceinline__ void gload16(const void* g, void* s){
    __builtin_amdgcn_global_load_lds(
        (const __attribute__((address_space(1))) void*)g,
        (__attribute__((address_space(3))) void*)s, 16, 0, 0);
}
// logical output col n -> physical B-panel slot (within each 64-block: s=(n&3)*16+(n>>2))
__device__ __forceinline__ int permslot(int n){
    return (n & ~63) | ((n & 3) << 4) | ((n >> 2) & 15);
}

// ---------------- CSR build ----------------
__global__ void k_count_deg(const int* __restrict__ dst, int* __restrict__ deg){
    int i = blockIdx.x*256 + threadIdx.x;
    if (i < EE) atomicAdd(&deg[dst[i]], 1);
}
__global__ void k_block_sum(const int* __restrict__ deg, int* __restrict__ bsum){
    __shared__ int s[1024];
    int i = blockIdx.x*1024 + threadIdx.x;
    s[threadIdx.x] = (i < NN) ? deg[i] : 0;
    __syncthreads();
    for (int o = 512; o > 0; o >>= 1){
        if (threadIdx.x < o) s[threadIdx.x] += s[threadIdx.x + o];
        __syncthreads();
    }
    if (threadIdx.x == 0) bsum[blockIdx.x] = s[0];
}
__global__ void k_make_off(const int* __restrict__ deg, const int* __restrict__ bsum,
                           int nb, int* __restrict__ off, int* __restrict__ pos,
                           float* __restrict__ invd){
    __shared__ int s[1024];
    __shared__ int base;
    int t = threadIdx.x;
    if (t < 64){
        int v = (t < blockIdx.x && t < nb) ? bsum[t] : 0;
        #pragma unroll
        for (int m = 1; m <= 32; m <<= 1) v += __shfl_xor(v, m);
        if (t == 0) base = v;
    }
    int i = blockIdx.x*1024 + t;
    int v0 = (i < NN) ? deg[i] : 0;
    s[t] = v0; __syncthreads();
    for (int o = 1; o < 1024; o <<= 1){
        int add = (t >= o) ? s[t - o] : 0;
        __syncthreads();
        s[t] += add;
        __syncthreads();
    }
    if (i < NN){
        int excl = s[t] - v0 + base;
        off[i] = excl; pos[i] = excl;
        invd[i] = 1.0f / fmaxf((float)v0, 1.0f);
    }
}
// XCD-binned scatter (round 13, confirmed): group g = blockIdx&7 owns dst range
// [g*6250,(g+1)*6250) -> each csr line dirtied by ONE XCD's L2 only.
__global__ __launch_bounds__(256) void k_build_csr(
    const int* __restrict__ src, const int* __restrict__ dst,
    int* __restrict__ pos, int* __restrict__ csr)
{
    const int grp = blockIdx.x & 7;
    const int bin = blockIdx.x >> 3;
    const int nbk = gridDim.x >> 3;
    const int lo  = grp * (NN/8);
    const int hi  = (grp == 7) ? NN : lo + (NN/8);
    for (int i = bin*256 + threadIdx.x; i < EE; i += nbk*256){
        int d = dst[i];
        if (d >= lo && d < hi){
            int p = atomicAdd(&pos[d], 1);
            csr[p] = src[i];
        }
    }
}

// ---------------- fused prep: cast x, Wp, [Wl|Wr] to bf16 (weights column-permuted) ----------------
#define NX  (NN*FIN/4)
#define NWP (HH*FIN/4)
#define NWC (NL*HH*2*HH/4)
__global__ void k_prep(const float* __restrict__ x, const float* __restrict__ Wp,
                       const float* __restrict__ Wl, const float* __restrict__ Wr,
                       unsigned short* __restrict__ Xb, unsigned short* __restrict__ Wpb,
                       unsigned short* __restrict__ Wb){
    int i = blockIdx.x*256 + threadIdx.x;
    if (i < NX){
        float4 v = *(const float4*)&x[i*4];
        u16x4 o; o[0]=f2bf(v.x); o[1]=f2bf(v.y); o[2]=f2bf(v.z); o[3]=f2bf(v.w);
        __builtin_nontemporal_store(o, (u16x4*)&Xb[i*4]);
        return;
    }
    int j = i - NX;
    if (j < NWP){
        int base = j*4;
        int kk = base & (FIN-1);
        int n  = base >> 7;
        float4 v = *(const float4*)&Wp[base];
        u16x4 o; o[0]=f2bf(v.x); o[1]=f2bf(v.y); o[2]=f2bf(v.z); o[3]=f2bf(v.w);
        *(u16x4*)&Wpb[permslot(n)*FIN + kk] = o;
        return;
    }
    int k4 = j - NWP;
    if (k4 < NWC){
        int base = k4*4;
        int kk  = base & 511;
        int n   = (base >> 9) & (HH-1);
        int lyr = base >> 17;
        const float* srcp = (kk < HH) ? &Wl[((size_t)lyr*HH + n)*HH + kk]
                                      : &Wr[((size_t)lyr*HH + n)*HH + (kk - HH)];
        float4 v = *(const float4*)srcp;
        u16x4 o; o[0]=f2bf(v.x); o[1]=f2bf(v.y); o[2]=f2bf(v.z); o[3]=f2bf(v.w);
        *(u16x4*)&Wb[(size_t)lyr*HH*2*HH + permslot(n)*2*HH + kk] = o;
    }
}

// ---------------- aggregation: u8 rows (256B) in, bf16 out (nt stores) ----------------
__device__ __forceinline__ void accum16(float* a, uint4 v, float c){
    const unsigned int w0 = v.x, w1 = v.y, w2 = v.z, w3 = v.w;
    #pragma unroll
    for (int b = 0; b < 4; ++b){
        a[b]    += c * (float)((w0 >> (8*b)) & 0xFF);
        a[4+b]  += c * (float)((w1 >> (8*b)) & 0xFF);
        a[8+b]  += c * (float)((w2 >> (8*b)) & 0xFF);
        a[12+b] += c * (float)((w3 >> (8*b)) & 0xFF);
    }
}

__global__ __launch_bounds__(256) void k_aggregate_u8(
    const unsigned char* __restrict__ hu, const float* __restrict__ scl,
    const int* __restrict__ csr, const int* __restrict__ off,
    const int* __restrict__ deg, const float* __restrict__ invd,
    unsigned short* __restrict__ aggb)
{
    const int wave = threadIdx.x >> 6, lane = threadIdx.x & 63;
    const int node = blockIdx.x*4 + wave;
    if (node >= NN) return;
    const int o = off[node], d = deg[node];
    const int grp = lane >> 4;
    const int fl  = lane & 15;

    float acc[16] = {};
    int j = 0;
    for (; j + 16 <= d; j += 16){
        int s0 = csr[o + j      + grp];
        int s1 = csr[o + j + 4  + grp];
        int s2 = csr[o + j + 8  + grp];
        int s3 = csr[o + j + 12 + grp];
        float c0 = scl[s0], c1 = scl[s1], c2 = scl[s2], c3 = scl[s3];
        uint4 v0 = *(const uint4*)&hu[(size_t)s0*HH + fl*16];
        uint4 v1 = *(const uint4*)&hu[(size_t)s1*HH + fl*16];
        uint4 v2 = *(const uint4*)&hu[(size_t)s2*HH + fl*16];
        uint4 v3 = *(const uint4*)&hu[(size_t)s3*HH + fl*16];
        accum16(acc, v0, c0); accum16(acc, v1, c1);
        accum16(acc, v2, c2); accum16(acc, v3, c3);
    }
    for (; j + 8 <= d; j += 8){
        int s0 = csr[o + j     + grp];
        int s1 = csr[o + j + 4 + grp];
        float c0 = scl[s0], c1 = scl[s1];
        uint4 v0 = *(const uint4*)&hu[(size_t)s0*HH + fl*16];
        uint4 v1 = *(const uint4*)&hu[(size_t)s1*HH + fl*16];
        accum16(acc, v0, c0); accum16(acc, v1, c1);
    }
    for (; j < d; j += 4){
        int idx = j + grp;
        int s0 = 0; float c0 = 0.f;
        if (idx < d){ s0 = csr[o + idx]; c0 = scl[s0]; }
        uint4 v0 = *(const uint4*)&hu[(size_t)s0*HH + fl*16];
        accum16(acc, v0, c0);
    }
    #pragma unroll
    for (int k = 0; k < 16; ++k){
        acc[k] += __shfl_xor(acc[k], 16);
        acc[k] += __shfl_xor(acc[k], 32);
    }
    if (grp == 0){
        float id = invd[node];
        u16x8 r0, r1;
        #pragma unroll
        for (int k = 0; k < 8; ++k){
            r0[k] = f2bf(acc[k]*id);
            r1[k] = f2bf(acc[8+k]*id);
        }
        __builtin_nontemporal_store(r0, (u16x8*)&aggb[(size_t)node*HH + fl*16]);
        __builtin_nontemporal_store(r1, (u16x8*)&aggb[(size_t)node*HH + fl*16 + 8]);
    }
}

// ======== MFMA GEMM: 16 waves / 2 half-tiles; TRIPLE-buffered staging, ONE barrier/step ========
// (round-14 structure, best measured). Epilogue stores are NON-TEMPORAL (this round's probe:
// outputs are write-once/never-reread here -> bypass RFO/L2-writeback path).
// EPI 0: relu(C+bias) -> outb+hu+scl; EPI 1: +LN+res -> outb+hu+scl; EPI 2: -> outf f32.
template<int EPI>
__global__ __launch_bounds__(1024) void k_gemm_mfma(
    const unsigned short* __restrict__ A0, int lda0,
    const unsigned short* __restrict__ A1, int lda1,
    const unsigned short* __restrict__ Bt,
    const float* __restrict__ bias,
    const float* __restrict__ gamma, const float* __restrict__ beta,
    const unsigned short* __restrict__ resb,
    float* __restrict__ outf, unsigned short* __restrict__ outb,
    unsigned char* __restrict__ hu, float* __restrict__ scl,
    int K0, int KTOT)
{
    __shared__ char smem[3*TB];   // 72 KB
    const int t    = threadIdx.x;
    const int w    = t >> 6, l = t & 63;
    const int lr   = l & 15, lg = l >> 4;
    const int half = w >> 3;                 // which 64-row half-tile
    const int wh   = w & 7;                  // wave within half
    const int wm   = wh >> 2, wn = wh & 3;   // 2 x 4 wave grid per half
    const int m0h  = blockIdx.x * BM + half*64;

    // ---- B staging: 1024 16B-units, 1/thread; pre-swizzled global source ----
    const int rowB = t >> 2;
    const int swzB = ((t & 3)*16) ^ ((rowB & 6) << 3);
    const char* bsrc = (const char*)(Bt + (size_t)rowB*KTOT) + swzB;
    const int bdstB = t*16;
    // ---- A staging: 256 units per half (waves 0-3 of each half) ----
    const int ua   = t & 255;
    const int rowA = ua >> 2;
    const int swzA = ((ua & 3)*16) ^ ((rowA & 6) << 3);
    int growA = m0h + rowA; if (growA > NN-1) growA = NN-1;
    const char* a0src = (const char*)(A0 + (size_t)growA*lda0) + swzA;
    const char* a1src = (const char*)(A1 + (size_t)growA*lda1) + swzA;
    const int adst = 16384 + half*4096 + ua*16;
    const bool hasA = (wh < 4);   // wave-uniform

    f32x4 acc[2][4] = {};

    auto stage = [&](int s, int buf){
        const int k0 = s * BK;
        char* base = smem + buf*TB;
        if (hasA){
            const char* g = (k0 < K0) ? (a0src + (size_t)k0*2)
                                      : (a1src + (size_t)(k0 - K0)*2);
            gload16(g, base + adst);
        }
        gload16(bsrc + (size_t)k0*2, base + bdstB);
    };

    const int nsteps = KTOT / BK;
    stage(0, 0);
    int buf = 0;
    for (int s = 0; s < nsteps; ++s){
        int nbuf = (buf == 2) ? 0 : buf + 1;
        if (s + 1 < nsteps){
            stage(s + 1, nbuf);
            if (hasA) { asm volatile("s_waitcnt vmcnt(2)" ::: "memory"); }
            else      { asm volatile("s_waitcnt vmcnt(1)" ::: "memory"); }
        } else {
            asm volatile("s_waitcnt vmcnt(0)" ::: "memory");
        }
        __builtin_amdgcn_s_barrier();
        __builtin_amdgcn_sched_barrier(0);

        const char* As = smem + buf*TB + 16384 + half*4096;
        const char* Bs = smem + buf*TB;
        const int kb = lg * 16;
        const int sw = (lr & 6) << 3;
        bf16x8 af[2], bfr[4];
        #pragma unroll
        for (int m = 0; m < 2; ++m){
            int r = wm*32 + m*16 + lr;
            af[m] = *(const bf16x8*)(As + r*64 + (kb ^ sw));
        }
        #pragma unroll
        for (int n = 0; n < 4; ++n){
            int r = wn*64 + n*16 + lr;
            bfr[n] = *(const bf16x8*)(Bs + r*64 + (kb ^ sw));
        }
        #pragma unroll
        for (int m = 0; m < 2; ++m)
            #pragma unroll
            for (int n = 0; n < 4; ++n)
                acc[m][n] = __builtin_amdgcn_mfma_f32_16x16x32_bf16(af[m], bfr[n], acc[m][n], 0, 0, 0);

        buf = nbuf;
    }
    __syncthreads();   // all waves done with staging LDS before epilogue reuse

    // ================= epilogue (register-packed; per-half reductions; NT stores) =================
    const int cb = wn*64 + lr*4;
    float4 bq = *(const float4*)&bias[cb];
    float bcol[4] = {bq.x, bq.y, bq.z, bq.w};
    float gcol[4], becol[4];
    if (EPI >= 1){
        float4 gq = *(const float4*)&gamma[cb];
        float4 eq = *(const float4*)&beta[cb];
        gcol[0]=gq.x; gcol[1]=gq.y; gcol[2]=gq.z; gcol[3]=gq.w;
        becol[0]=eq.x; becol[1]=eq.y; becol[2]=eq.z; becol[3]=eq.w;
    }

    float* red  = (float*)(smem + half*4096);   // [4 wn][64 R][2] per half (2 KB)
    float* red2 = red + 512;                    // row max (1 KB)
    float pmx[2][4];

    if (EPI == 0){
        #pragma unroll
        for (int m = 0; m < 2; ++m)
        #pragma unroll
        for (int reg = 0; reg < 4; ++reg){
            int R = wm*32 + m*16 + lg*4 + reg;
            int grow = m0h + R;
            float mx = 0.f;
            u16x4 hb4;
            #pragma unroll
            for (int n = 0; n < 4; ++n){
                float v = fmaxf(acc[m][n][reg] + bcol[n], 0.f);
                acc[m][n][reg] = v;
                mx = fmaxf(mx, v);
                hb4[n] = f2bf(v);
            }
            if (grow < NN) __builtin_nontemporal_store(hb4, (u16x4*)&outb[(size_t)grow*HH + cb]);
            pmx[m][reg] = mx;
        }
    } else {
        float sm[2][4], sq[2][4];
        #pragma unroll
        for (int m = 0; m < 2; ++m)
        #pragma unroll
        for (int reg = 0; reg < 4; ++reg){
            float s = 0.f, q = 0.f;
            #pragma unroll
            for (int n = 0; n < 4; ++n){
                float v = acc[m][n][reg] + bcol[n];
                acc[m][n][reg] = v;
                s += v; q += v*v;
            }
            sm[m][reg] = s; sq[m][reg] = q;
        }
        #pragma unroll
        for (int mask = 1; mask <= 8; mask <<= 1){
            #pragma unroll
            for (int m = 0; m < 2; ++m)
            #pragma unroll
            for (int reg = 0; reg < 4; ++reg){
                sm[m][reg] += __shfl_xor(sm[m][reg], mask);
                sq[m][reg] += __shfl_xor(sq[m][reg], mask);
            }
        }
        if (lr == 0){
            #pragma unroll
            for (int m = 0; m < 2; ++m)
            #pragma unroll
            for (int reg = 0; reg < 4; ++reg){
                int R = wm*32 + m*16 + lg*4 + reg;
                red[(wn*64 + R)*2 + 0] = sm[m][reg];
                red[(wn*64 + R)*2 + 1] = sq[m][reg];
            }
        }
        __syncthreads();
        #pragma unroll
        for (int m = 0; m < 2; ++m)
        #pragma unroll
        for (int reg = 0; reg < 4; ++reg){
            int R = wm*32 + m*16 + lg*4 + reg;
            float S = 0.f, Q = 0.f;
            #pragma unroll
            for (int ww = 0; ww < 4; ++ww){
                S += red[(ww*64 + R)*2 + 0];
                Q += red[(ww*64 + R)*2 + 1];
            }
            float mean = S * (1.0f/HH);
            float var  = Q * (1.0f/HH) - mean*mean;
            float inv  = rsqrtf(var + 1e-5f);
            int grow = m0h + R;
            int growc = (grow > NN-1) ? NN-1 : grow;
            ushort4 rv = *(const ushort4*)&resb[(size_t)growc*HH + cb];
            float mx = 0.f;
            u16x4 hb4;
            f32x4 fo;
            #pragma unroll
            for (int n = 0; n < 4; ++n){
                float o = fmaxf((acc[m][n][reg] - mean)*inv*gcol[n] + becol[n], 0.f)
                          + bf2f(((const unsigned short*)&rv)[n]);
                acc[m][n][reg] = o;
                mx = fmaxf(mx, o);
                if (EPI == 1) hb4[n] = f2bf(o);
                else          fo[n] = o;
            }
            if (grow < NN){
                if (EPI == 1) __builtin_nontemporal_store(hb4, (u16x4*)&outb[(size_t)grow*HH + cb]);
                else          __builtin_nontemporal_store(fo, (f32x4*)&outf[(size_t)grow*HH + cb]);
            }
            pmx[m][reg] = mx;
        }
    }

    if (EPI <= 1){
        #pragma unroll
        for (int mask = 1; mask <= 8; mask <<= 1){
            #pragma unroll
            for (int m = 0; m < 2; ++m)
            #pragma unroll
            for (int reg = 0; reg < 4; ++reg)
                pmx[m][reg] = fmaxf(pmx[m][reg], __shfl_xor(pmx[m][reg], mask));
        }
        if (EPI == 0) __syncthreads();
        if (lr == 0){
            #pragma unroll
            for (int m = 0; m < 2; ++m)
            #pragma unroll
            for (int reg = 0; reg < 4; ++reg){
                int R = wm*32 + m*16 + lg*4 + reg;
                red2[wn*64 + R] = pmx[m][reg];
            }
        }
        __syncthreads();
        #pragma unroll
        for (int m = 0; m < 2; ++m)
        #pragma unroll
        for (int reg = 0; reg < 4; ++reg){
            int R = wm*32 + m*16 + lg*4 + reg;
            float rmax = fmaxf(fmaxf(red2[R], red2[64 + R]),
                               fmaxf(red2[128 + R], red2[192 + R]));
            float qinv = (rmax > 0.f) ? (255.0f / rmax) : 0.f;
            int grow = m0h + R;
            if (grow >= NN) continue;
            unsigned int q4 = 0;
            #pragma unroll
            for (int n = 0; n < 4; ++n){
                unsigned int qv = (unsigned int)(acc[m][n][reg]*qinv + 0.5f);
                q4 |= qv << (8*n);
            }
            __builtin_nontemporal_store(q4, (unsigned int*)&hu[(size_t)grow*HH + cb]);
            if (wn == 0 && lr == 0) scl[grow] = rmax * (1.0f/255.0f);
        }
    }
}

// ---------------- host ----------------
extern "C" void kernel_launch(void* const* d_in, const int* in_sizes, int n_in,
                              void* d_out, int out_size, void* d_ws, size_t ws_size,
                              hipStream_t stream) {
    const float* x     = (const float*)d_in[0];
    const int*   ei    = (const int*)d_in[1];
    const int*   srcI  = ei;
    const int*   dstI  = ei + EE;
    const float* Wp    = (const float*)d_in[2];
    const float* bp    = (const float*)d_in[3];
    const float* Wl    = (const float*)d_in[4];
    const float* bl    = (const float*)d_in[5];
    const float* Wr    = (const float*)d_in[6];
    const float* gamma = (const float*)d_in[7];
    const float* beta  = (const float*)d_in[8];
    float* out = (float*)d_out;

    char* ws = (char*)d_ws;
    size_t off_b = 0;
    auto alloc = [&](size_t bytes) -> char* {
        char* p = ws + off_b;
        off_b = (off_b + bytes + 255) & ~(size_t)255;
        return p;
    };
    unsigned short* Hb0  = (unsigned short*)alloc((size_t)NN*HH*2);
    unsigned short* Hb1  = (unsigned short*)alloc((size_t)NN*HH*2);
    unsigned short* AGGb = (unsigned short*)alloc((size_t)NN*HH*2);
    unsigned char*  Hu0  = (unsigned char*)alloc((size_t)NN*HH);
    unsigned char*  Hu1  = (unsigned char*)alloc((size_t)NN*HH);
    float* Scl0 = (float*)alloc((size_t)NN*4);
    float* Scl1 = (float*)alloc((size_t)NN*4);
    unsigned short* Xb = (unsigned short*)alloc((size_t)NN*FIN*2);
    int*   csr  = (int*)alloc((size_t)EE*4);
    int*   deg  = (int*)alloc((size_t)NN*4);
    int*   offs = (int*)alloc((size_t)NN*4);
    int*   pos  = (int*)alloc((size_t)NN*4);
    float* invd = (float*)alloc((size_t)NN*4);
    int*   bsum = (int*)alloc(64*4);
    unsigned short* Wpb = (unsigned short*)alloc((size_t)HH*FIN*2);
    unsigned short* Wb  = (unsigned short*)alloc((size_t)NL*HH*2*HH*2);
    (void)ws_size; (void)in_sizes; (void)n_in; (void)out_size;

    const int NB = (NN + 1023)/1024;   // 49

    (void)hipMemsetAsync(deg, 0, (size_t)NN*4, stream);
    k_count_deg<<<(EE + 255)/256, 256, 0, stream>>>(dstI, deg);
    k_block_sum<<<NB, 1024, 0, stream>>>(deg, bsum);
    k_make_off<<<NB, 1024, 0, stream>>>(deg, bsum, NB, offs, pos, invd);
    k_prep<<<(NX + NWP + NWC + 255)/256, 256, 0, stream>>>(x, Wp, Wl, Wr, Xb, Wpb, Wb);
    k_build_csr<<<1024, 256, 0, stream>>>(srcI, dstI, pos, csr);

    const int GB = (NN + BM - 1)/BM;  // 391

    // input projection + ReLU -> Hb0 (bf16) + Hu0/Scl0 (u8)
    k_gemm_mfma<0><<<GB, 1024, 0, stream>>>(Xb, FIN, Xb, FIN, Wpb, bp,
                                            nullptr, nullptr, nullptr,
                                            nullptr, Hb0, Hu0, Scl0,
                                            FIN, FIN);

    unsigned short* hin = Hb0;
    unsigned char*  huin = Hu0;
    float*          sclin = Scl0;
    for (int lyr = 0; lyr < NL; ++lyr){
        k_aggregate_u8<<<(NN + 3)/4, 256, 0, stream>>>(huin, sclin, csr, offs, deg,
                                                       invd, AGGb);
        unsigned short* hout  = (hin == Hb0) ? Hb1 : Hb0;
        unsigned char*  huout = (huin == Hu0) ? Hu1 : Hu0;
        float*          sclout= (sclin == Scl0) ? Scl1 : Scl0;
        const unsigned short* Wbt = Wb + (size_t)lyr*HH*2*HH;
        if (lyr < NL-1)
            k_gemm_mfma<1><<<GB, 1024, 0, stream>>>(AGGb, HH, hin, HH, Wbt, bl + lyr*HH,
                                                    gamma + lyr*HH, beta + lyr*HH, hin,
                                                    nullptr, hout, huout, sclout,
                                                    HH, 2*HH);
        else
            k_gemm_mfma<2><<<GB, 1024, 0, stream>>>(AGGb, HH, hin, HH, Wbt, bl + lyr*HH,
                                                    gamma + lyr*HH, beta + lyr*HH, hin,
                                                    out, nullptr, nullptr, nullptr,
                                                    HH, 2*HH);
        hin = hout; huin = huout; sclin = sclout;
    }
}

// Round 20
// 341.339 us; speedup vs baseline: 1.0327x; 1.0327x over previous
//
#include <hip/hip_runtime.h>

#define NN 50000
#define EE 800000
#define FIN 128
#define HH 256
#define NL 3

#define BM 128                    // per block: 2 independent 64-row half-tiles
#define BK 32
#define TB (16384 + 8192)         // per staging buffer: B 16KB @0, A 8KB @16384
                                  // LDS = 3*TB = 72KB

typedef __bf16 bf16x8 __attribute__((ext_vector_type(8)));
typedef float  f32x4  __attribute__((ext_vector_type(4)));
typedef unsigned short u16x8 __attribute__((ext_vector_type(8)));

__device__ __forceinline__ float bf2f(unsigned short u){
    union { unsigned int i; float f; } v; v.i = ((unsigned int)u) << 16; return v.f;
}
__device__ __forceinline__ unsigned short f2bf(float f){
    union { float f; unsigned int i; } v; v.f = f;
    unsigned int r = v.i + 0x7FFF + ((v.i >> 16) & 1);  // RNE
    return (unsigned short)(r >> 16);
}
__device__ __forceinline__ void gload16(const void* g, void* s){
    __builtin_amdgcn_global_load_lds(
        (const __attribute__((address_space(1))) void*)g,
        (__attribute__((address_space(3))) void*)s, 16, 0, 0);
}
// logical output col n -> physical B-panel slot (within each 64-block: s=(n&3)*16+(n>>2))
__device__ __forceinline__ int permslot(int n){
    return (n & ~63) | ((n & 3) << 4) | ((n >> 2) & 15);
}

// ---------------- CSR build ----------------
__global__ void k_count_deg(const int* __restrict__ dst, int* __restrict__ deg){
    int i = blockIdx.x*256 + threadIdx.x;
    if (i < EE) atomicAdd(&deg[dst[i]], 1);
}
__global__ void k_block_sum(const int* __restrict__ deg, int* __restrict__ bsum){
    __shared__ int s[1024];
    int i = blockIdx.x*1024 + threadIdx.x;
    s[threadIdx.x] = (i < NN) ? deg[i] : 0;
    __syncthreads();
    for (int o = 512; o > 0; o >>= 1){
        if (threadIdx.x < o) s[threadIdx.x] += s[threadIdx.x + o];
        __syncthreads();
    }
    if (threadIdx.x == 0) bsum[blockIdx.x] = s[0];
}
__global__ void k_make_off(const int* __restrict__ deg, const int* __restrict__ bsum,
                           int nb, int* __restrict__ off, int* __restrict__ pos,
                           float* __restrict__ invd){
    __shared__ int s[1024];
    __shared__ int base;
    int t = threadIdx.x;
    if (t < 64){
        int v = (t < blockIdx.x && t < nb) ? bsum[t] : 0;
        #pragma unroll
        for (int m = 1; m <= 32; m <<= 1) v += __shfl_xor(v, m);
        if (t == 0) base = v;
    }
    int i = blockIdx.x*1024 + t;
    int v0 = (i < NN) ? deg[i] : 0;
    s[t] = v0; __syncthreads();
    for (int o = 1; o < 1024; o <<= 1){
        int add = (t >= o) ? s[t - o] : 0;
        __syncthreads();
        s[t] += add;
        __syncthreads();
    }
    if (i < NN){
        int excl = s[t] - v0 + base;
        off[i] = excl; pos[i] = excl;
        invd[i] = 1.0f / fmaxf((float)v0, 1.0f);
    }
}
// XCD-binned scatter (round 13, confirmed): group g = blockIdx&7 owns dst range
// [g*6250,(g+1)*6250) -> each csr line dirtied by ONE XCD's L2 only.
__global__ __launch_bounds__(256) void k_build_csr(
    const int* __restrict__ src, const int* __restrict__ dst,
    int* __restrict__ pos, int* __restrict__ csr)
{
    const int grp = blockIdx.x & 7;
    const int bin = blockIdx.x >> 3;
    const int nbk = gridDim.x >> 3;
    const int lo  = grp * (NN/8);
    const int hi  = (grp == 7) ? NN : lo + (NN/8);
    for (int i = bin*256 + threadIdx.x; i < EE; i += nbk*256){
        int d = dst[i];
        if (d >= lo && d < hi){
            int p = atomicAdd(&pos[d], 1);
            csr[p] = src[i];
        }
    }
}

// ---------------- fused prep: cast x, Wp, [Wl|Wr] to bf16 (weights column-permuted) ----------------
#define NX  (NN*FIN/4)
#define NWP (HH*FIN/4)
#define NWC (NL*HH*2*HH/4)
__global__ void k_prep(const float* __restrict__ x, const float* __restrict__ Wp,
                       const float* __restrict__ Wl, const float* __restrict__ Wr,
                       unsigned short* __restrict__ Xb, unsigned short* __restrict__ Wpb,
                       unsigned short* __restrict__ Wb){
    int i = blockIdx.x*256 + threadIdx.x;
    if (i < NX){
        float4 v = *(const float4*)&x[i*4];
        ushort4 o; o.x=f2bf(v.x); o.y=f2bf(v.y); o.z=f2bf(v.z); o.w=f2bf(v.w);
        *(ushort4*)&Xb[i*4] = o;
        return;
    }
    int j = i - NX;
    if (j < NWP){
        int base = j*4;
        int kk = base & (FIN-1);
        int n  = base >> 7;
        float4 v = *(const float4*)&Wp[base];
        ushort4 o; o.x=f2bf(v.x); o.y=f2bf(v.y); o.z=f2bf(v.z); o.w=f2bf(v.w);
        *(ushort4*)&Wpb[permslot(n)*FIN + kk] = o;
        return;
    }
    int k4 = j - NWP;
    if (k4 < NWC){
        int base = k4*4;
        int kk  = base & 511;
        int n   = (base >> 9) & (HH-1);
        int lyr = base >> 17;
        const float* srcp = (kk < HH) ? &Wl[((size_t)lyr*HH + n)*HH + kk]
                                      : &Wr[((size_t)lyr*HH + n)*HH + (kk - HH)];
        float4 v = *(const float4*)srcp;
        ushort4 o; o.x=f2bf(v.x); o.y=f2bf(v.y); o.z=f2bf(v.z); o.w=f2bf(v.w);
        *(ushort4*)&Wb[(size_t)lyr*HH*2*HH + permslot(n)*2*HH + kk] = o;
    }
}

// ---------------- aggregation: u8 rows (256B) in, bf16 out ----------------
__device__ __forceinline__ void accum16(float* a, uint4 v, float c){
    const unsigned int w0 = v.x, w1 = v.y, w2 = v.z, w3 = v.w;
    #pragma unroll
    for (int b = 0; b < 4; ++b){
        a[b]    += c * (float)((w0 >> (8*b)) & 0xFF);
        a[4+b]  += c * (float)((w1 >> (8*b)) & 0xFF);
        a[8+b]  += c * (float)((w2 >> (8*b)) & 0xFF);
        a[12+b] += c * (float)((w3 >> (8*b)) & 0xFF);
    }
}

__global__ __launch_bounds__(256) void k_aggregate_u8(
    const unsigned char* __restrict__ hu, const float* __restrict__ scl,
    const int* __restrict__ csr, const int* __restrict__ off,
    const int* __restrict__ deg, const float* __restrict__ invd,
    unsigned short* __restrict__ aggb)
{
    const int wave = threadIdx.x >> 6, lane = threadIdx.x & 63;
    const int node = blockIdx.x*4 + wave;
    if (node >= NN) return;
    const int o = off[node], d = deg[node];
    const int grp = lane >> 4;
    const int fl  = lane & 15;

    float acc[16] = {};
    int j = 0;
    for (; j + 16 <= d; j += 16){
        int s0 = csr[o + j      + grp];
        int s1 = csr[o + j + 4  + grp];
        int s2 = csr[o + j + 8  + grp];
        int s3 = csr[o + j + 12 + grp];
        float c0 = scl[s0], c1 = scl[s1], c2 = scl[s2], c3 = scl[s3];
        uint4 v0 = *(const uint4*)&hu[(size_t)s0*HH + fl*16];
        uint4 v1 = *(const uint4*)&hu[(size_t)s1*HH + fl*16];
        uint4 v2 = *(const uint4*)&hu[(size_t)s2*HH + fl*16];
        uint4 v3 = *(const uint4*)&hu[(size_t)s3*HH + fl*16];
        accum16(acc, v0, c0); accum16(acc, v1, c1);
        accum16(acc, v2, c2); accum16(acc, v3, c3);
    }
    for (; j + 8 <= d; j += 8){
        int s0 = csr[o + j     + grp];
        int s1 = csr[o + j + 4 + grp];
        float c0 = scl[s0], c1 = scl[s1];
        uint4 v0 = *(const uint4*)&hu[(size_t)s0*HH + fl*16];
        uint4 v1 = *(const uint4*)&hu[(size_t)s1*HH + fl*16];
        accum16(acc, v0, c0); accum16(acc, v1, c1);
    }
    for (; j < d; j += 4){
        int idx = j + grp;
        int s0 = 0; float c0 = 0.f;
        if (idx < d){ s0 = csr[o + idx]; c0 = scl[s0]; }
        uint4 v0 = *(const uint4*)&hu[(size_t)s0*HH + fl*16];
        accum16(acc, v0, c0);
    }
    #pragma unroll
    for (int k = 0; k < 16; ++k){
        acc[k] += __shfl_xor(acc[k], 16);
        acc[k] += __shfl_xor(acc[k], 32);
    }
    if (grp == 0){
        float id = invd[node];
        u16x8 r0, r1;
        #pragma unroll
        for (int k = 0; k < 8; ++k){
            r0[k] = f2bf(acc[k]*id);
            r1[k] = f2bf(acc[8+k]*id);
        }
        *(u16x8*)&aggb[(size_t)node*HH + fl*16]     = r0;
        *(u16x8*)&aggb[(size_t)node*HH + fl*16 + 8] = r1;
    }
}

// ======== MFMA GEMM: 16 waves / 2 half-tiles; TRIPLE-buffered staging, ONE barrier/step ========
// Round-14 structure (measured best). Register-packed permuted epilogue, normal stores.
// EPI 0: relu(C+bias) -> outb+hu+scl; EPI 1: +LN+res -> outb+hu+scl; EPI 2: -> outf f32.
template<int EPI>
__global__ __launch_bounds__(1024) void k_gemm_mfma(
    const unsigned short* __restrict__ A0, int lda0,
    const unsigned short* __restrict__ A1, int lda1,
    const unsigned short* __restrict__ Bt,
    const float* __restrict__ bias,
    const float* __restrict__ gamma, const float* __restrict__ beta,
    const unsigned short* __restrict__ resb,
    float* __restrict__ outf, unsigned short* __restrict__ outb,
    unsigned char* __restrict__ hu, float* __restrict__ scl,
    int K0, int KTOT)
{
    __shared__ char smem[3*TB];   // 72 KB
    const int t    = threadIdx.x;
    const int w    = t >> 6, l = t & 63;
    const int lr   = l & 15, lg = l >> 4;
    const int half = w >> 3;                 // which 64-row half-tile
    const int wh   = w & 7;                  // wave within half
    const int wm   = wh >> 2, wn = wh & 3;   // 2 x 4 wave grid per half
    const int m0h  = blockIdx.x * BM + half*64;

    // ---- B staging: 1024 16B-units, 1/thread; pre-swizzled global source ----
    const int rowB = t >> 2;
    const int swzB = ((t & 3)*16) ^ ((rowB & 6) << 3);
    const char* bsrc = (const char*)(Bt + (size_t)rowB*KTOT) + swzB;
    const int bdstB = t*16;
    // ---- A staging: 256 units per half (waves 0-3 of each half) ----
    const int ua   = t & 255;
    const int rowA = ua >> 2;
    const int swzA = ((ua & 3)*16) ^ ((rowA & 6) << 3);
    int growA = m0h + rowA; if (growA > NN-1) growA = NN-1;
    const char* a0src = (const char*)(A0 + (size_t)growA*lda0) + swzA;
    const char* a1src = (const char*)(A1 + (size_t)growA*lda1) + swzA;
    const int adst = 16384 + half*4096 + ua*16;
    const bool hasA = (wh < 4);   // wave-uniform

    f32x4 acc[2][4] = {};

    auto stage = [&](int s, int buf){
        const int k0 = s * BK;
        char* base = smem + buf*TB;
        if (hasA){
            const char* g = (k0 < K0) ? (a0src + (size_t)k0*2)
                                      : (a1src + (size_t)(k0 - K0)*2);
            gload16(g, base + adst);
        }
        gload16(bsrc + (size_t)k0*2, base + bdstB);
    };

    const int nsteps = KTOT / BK;
    stage(0, 0);
    int buf = 0;
    for (int s = 0; s < nsteps; ++s){
        int nbuf = (buf == 2) ? 0 : buf + 1;
        if (s + 1 < nsteps){
            stage(s + 1, nbuf);
            if (hasA) { asm volatile("s_waitcnt vmcnt(2)" ::: "memory"); }
            else      { asm volatile("s_waitcnt vmcnt(1)" ::: "memory"); }
        } else {
            asm volatile("s_waitcnt vmcnt(0)" ::: "memory");
        }
        __builtin_amdgcn_s_barrier();
        __builtin_amdgcn_sched_barrier(0);

        const char* As = smem + buf*TB + 16384 + half*4096;
        const char* Bs = smem + buf*TB;
        const int kb = lg * 16;
        const int sw = (lr & 6) << 3;
        bf16x8 af[2], bfr[4];
        #pragma unroll
        for (int m = 0; m < 2; ++m){
            int r = wm*32 + m*16 + lr;
            af[m] = *(const bf16x8*)(As + r*64 + (kb ^ sw));
        }
        #pragma unroll
        for (int n = 0; n < 4; ++n){
            int r = wn*64 + n*16 + lr;
            bfr[n] = *(const bf16x8*)(Bs + r*64 + (kb ^ sw));
        }
        #pragma unroll
        for (int m = 0; m < 2; ++m)
            #pragma unroll
            for (int n = 0; n < 4; ++n)
                acc[m][n] = __builtin_amdgcn_mfma_f32_16x16x32_bf16(af[m], bfr[n], acc[m][n], 0, 0, 0);

        buf = nbuf;
    }
    __syncthreads();   // all waves done with staging LDS before epilogue reuse

    // ================= epilogue (register-packed; per-half reductions) =================
    const int cb = wn*64 + lr*4;
    float4 bq = *(const float4*)&bias[cb];
    float bcol[4] = {bq.x, bq.y, bq.z, bq.w};
    float gcol[4], becol[4];
    if (EPI >= 1){
        float4 gq = *(const float4*)&gamma[cb];
        float4 eq = *(const float4*)&beta[cb];
        gcol[0]=gq.x; gcol[1]=gq.y; gcol[2]=gq.z; gcol[3]=gq.w;
        becol[0]=eq.x; becol[1]=eq.y; becol[2]=eq.z; becol[3]=eq.w;
    }

    float* red  = (float*)(smem + half*4096);   // [4 wn][64 R][2] per half (2 KB)
    float* red2 = red + 512;                    // row max (1 KB)
    float pmx[2][4];

    if (EPI == 0){
        #pragma unroll
        for (int m = 0; m < 2; ++m)
        #pragma unroll
        for (int reg = 0; reg < 4; ++reg){
            int R = wm*32 + m*16 + lg*4 + reg;
            int grow = m0h + R;
            float mx = 0.f;
            ushort4 hb4;
            #pragma unroll
            for (int n = 0; n < 4; ++n){
                float v = fmaxf(acc[m][n][reg] + bcol[n], 0.f);
                acc[m][n][reg] = v;
                mx = fmaxf(mx, v);
                ((unsigned short*)&hb4)[n] = f2bf(v);
            }
            if (grow < NN) *(ushort4*)&outb[(size_t)grow*HH + cb] = hb4;
            pmx[m][reg] = mx;
        }
    } else {
        float sm[2][4], sq[2][4];
        #pragma unroll
        for (int m = 0; m < 2; ++m)
        #pragma unroll
        for (int reg = 0; reg < 4; ++reg){
            float s = 0.f, q = 0.f;
            #pragma unroll
            for (int n = 0; n < 4; ++n){
                float v = acc[m][n][reg] + bcol[n];
                acc[m][n][reg] = v;
                s += v; q += v*v;
            }
            sm[m][reg] = s; sq[m][reg] = q;
        }
        #pragma unroll
        for (int mask = 1; mask <= 8; mask <<= 1){
            #pragma unroll
            for (int m = 0; m < 2; ++m)
            #pragma unroll
            for (int reg = 0; reg < 4; ++reg){
                sm[m][reg] += __shfl_xor(sm[m][reg], mask);
                sq[m][reg] += __shfl_xor(sq[m][reg], mask);
            }
        }
        if (lr == 0){
            #pragma unroll
            for (int m = 0; m < 2; ++m)
            #pragma unroll
            for (int reg = 0; reg < 4; ++reg){
                int R = wm*32 + m*16 + lg*4 + reg;
                red[(wn*64 + R)*2 + 0] = sm[m][reg];
                red[(wn*64 + R)*2 + 1] = sq[m][reg];
            }
        }
        __syncthreads();
        #pragma unroll
        for (int m = 0; m < 2; ++m)
        #pragma unroll
        for (int reg = 0; reg < 4; ++reg){
            int R = wm*32 + m*16 + lg*4 + reg;
            float S = 0.f, Q = 0.f;
            #pragma unroll
            for (int ww = 0; ww < 4; ++ww){
                S += red[(ww*64 + R)*2 + 0];
                Q += red[(ww*64 + R)*2 + 1];
            }
            float mean = S * (1.0f/HH);
            float var  = Q * (1.0f/HH) - mean*mean;
            float inv  = rsqrtf(var + 1e-5f);
            int grow = m0h + R;
            int growc = (grow > NN-1) ? NN-1 : grow;
            ushort4 rv = *(const ushort4*)&resb[(size_t)growc*HH + cb];
            float mx = 0.f;
            ushort4 hb4;
            f32x4 fo;
            #pragma unroll
            for (int n = 0; n < 4; ++n){
                float o = fmaxf((acc[m][n][reg] - mean)*inv*gcol[n] + becol[n], 0.f)
                          + bf2f(((const unsigned short*)&rv)[n]);
                acc[m][n][reg] = o;
                mx = fmaxf(mx, o);
                if (EPI == 1) ((unsigned short*)&hb4)[n] = f2bf(o);
                else          fo[n] = o;
            }
            if (grow < NN){
                if (EPI == 1) *(ushort4*)&outb[(size_t)grow*HH + cb] = hb4;
                else          *(f32x4*)&outf[(size_t)grow*HH + cb] = fo;
            }
            pmx[m][reg] = mx;
        }
    }

    if (EPI <= 1){
        #pragma unroll
        for (int mask = 1; mask <= 8; mask <<= 1){
            #pragma unroll
            for (int m = 0; m < 2; ++m)
            #pragma unroll
            for (int reg = 0; reg < 4; ++reg)
                pmx[m][reg] = fmaxf(pmx[m][reg], __shfl_xor(pmx[m][reg], mask));
        }
        if (EPI == 0) __syncthreads();
        if (lr == 0){
            #pragma unroll
            for (int m = 0; m < 2; ++m)
            #pragma unroll
            for (int reg = 0; reg < 4; ++reg){
                int R = wm*32 + m*16 + lg*4 + reg;
                red2[wn*64 + R] = pmx[m][reg];
            }
        }
        __syncthreads();
        #pragma unroll
        for (int m = 0; m < 2; ++m)
        #pragma unroll
        for (int reg = 0; reg < 4; ++reg){
            int R = wm*32 + m*16 + lg*4 + reg;
            float rmax = fmaxf(fmaxf(red2[R], red2[64 + R]),
                               fmaxf(red2[128 + R], red2[192 + R]));
            float qinv = (rmax > 0.f) ? (255.0f / rmax) : 0.f;
            int grow = m0h + R;
            if (grow >= NN) continue;
            unsigned int q4 = 0;
            #pragma unroll
            for (int n = 0; n < 4; ++n){
                unsigned int qv = (unsigned int)(acc[m][n][reg]*qinv + 0.5f);
                q4 |= qv << (8*n);
            }
            *(unsigned int*)&hu[(size_t)grow*HH + cb] = q4;
            if (wn == 0 && lr == 0) scl[grow] = rmax * (1.0f/255.0f);
        }
    }
}

// ---------------- host ----------------
extern "C" void kernel_launch(void* const* d_in, const int* in_sizes, int n_in,
                              void* d_out, int out_size, void* d_ws, size_t ws_size,
                              hipStream_t stream) {
    const float* x     = (const float*)d_in[0];
    const int*   ei    = (const int*)d_in[1];
    const int*   srcI  = ei;
    const int*   dstI  = ei + EE;
    const float* Wp    = (const float*)d_in[2];
    const float* bp    = (const float*)d_in[3];
    const float* Wl    = (const float*)d_in[4];
    const float* bl    = (const float*)d_in[5];
    const float* Wr    = (const float*)d_in[6];
    const float* gamma = (const float*)d_in[7];
    const float* beta  = (const float*)d_in[8];
    float* out = (float*)d_out;

    char* ws = (char*)d_ws;
    size_t off_b = 0;
    auto alloc = [&](size_t bytes) -> char* {
        char* p = ws + off_b;
        off_b = (off_b + bytes + 255) & ~(size_t)255;
        return p;
    };
    unsigned short* Hb0  = (unsigned short*)alloc((size_t)NN*HH*2);
    unsigned short* Hb1  = (unsigned short*)alloc((size_t)NN*HH*2);
    unsigned short* AGGb = (unsigned short*)alloc((size_t)NN*HH*2);
    unsigned char*  Hu0  = (unsigned char*)alloc((size_t)NN*HH);
    unsigned char*  Hu1  = (unsigned char*)alloc((size_t)NN*HH);
    float* Scl0 = (float*)alloc((size_t)NN*4);
    float* Scl1 = (float*)alloc((size_t)NN*4);
    unsigned short* Xb = (unsigned short*)alloc((size_t)NN*FIN*2);
    int*   csr  = (int*)alloc((size_t)EE*4);
    int*   deg  = (int*)alloc((size_t)NN*4);
    int*   offs = (int*)alloc((size_t)NN*4);
    int*   pos  = (int*)alloc((size_t)NN*4);
    float* invd = (float*)alloc((size_t)NN*4);
    int*   bsum = (int*)alloc(64*4);
    unsigned short* Wpb = (unsigned short*)alloc((size_t)HH*FIN*2);
    unsigned short* Wb  = (unsigned short*)alloc((size_t)NL*HH*2*HH*2);
    (void)ws_size; (void)in_sizes; (void)n_in; (void)out_size;

    const int NB = (NN + 1023)/1024;   // 49

    (void)hipMemsetAsync(deg, 0, (size_t)NN*4, stream);
    k_count_deg<<<(EE + 255)/256, 256, 0, stream>>>(dstI, deg);
    k_block_sum<<<NB, 1024, 0, stream>>>(deg, bsum);
    k_make_off<<<NB, 1024, 0, stream>>>(deg, bsum, NB, offs, pos, invd);
    k_prep<<<(NX + NWP + NWC + 255)/256, 256, 0, stream>>>(x, Wp, Wl, Wr, Xb, Wpb, Wb);
    k_build_csr<<<1024, 256, 0, stream>>>(srcI, dstI, pos, csr);

    const int GB = (NN + BM - 1)/BM;  // 391

    // input projection + ReLU -> Hb0 (bf16) + Hu0/Scl0 (u8)
    k_gemm_mfma<0><<<GB, 1024, 0, stream>>>(Xb, FIN, Xb, FIN, Wpb, bp,
                                            nullptr, nullptr, nullptr,
                                            nullptr, Hb0, Hu0, Scl0,
                                            FIN, FIN);

    unsigned short* hin = Hb0;
    unsigned char*  huin = Hu0;
    float*          sclin = Scl0;
    for (int lyr = 0; lyr < NL; ++lyr){
        k_aggregate_u8<<<(NN + 3)/4, 256, 0, stream>>>(huin, sclin, csr, offs, deg,
                                                       invd, AGGb);
        unsigned short* hout  = (hin == Hb0) ? Hb1 : Hb0;
        unsigned char*  huout = (huin == Hu0) ? Hu1 : Hu0;
        float*          sclout= (sclin == Scl0) ? Scl1 : Scl0;
        const unsigned short* Wbt = Wb + (size_t)lyr*HH*2*HH;
        if (lyr < NL-1)
            k_gemm_mfma<1><<<GB, 1024, 0, stream>>>(AGGb, HH, hin, HH, Wbt, bl + lyr*HH,
                                                    gamma + lyr*HH, beta + lyr*HH, hin,
                                                    nullptr, hout, huout, sclout,
                                                    HH, 2*HH);
        else
            k_gemm_mfma<2><<<GB, 1024, 0, stream>>>(AGGb, HH, hin, HH, Wbt, bl + lyr*HH,
                                                    gamma + lyr*HH, beta + lyr*HH, hin,
                                                    out, nullptr, nullptr, nullptr,
                                                    HH, 2*HH);
        hin = hout; huin = huout; sclin = sclout;
    }
}